// Round 1
// baseline (1176.770 us; speedup 1.0000x reference)
//
#include <hip/hip_runtime.h>
#include <stdint.h>

// ---------------------------------------------------------------------------
// GNN MetaLayer on MI355X (gfx950). Dtype-self-detecting:
//   flags[0] = 1 if float tensors are f32 (else bf16), detected from x bits
//   flags[1] = 1 if edge_index is int64 (else int32), detected from odd words
// Compute: bf16 MFMA 16x16x32, f32 accumulate.
// Aggregation: NO float atomics. Counting-sort edges by row (histogram +
// single-block scan + scatter -> perm/rowstart CSR), then a gather-based
// segment-mean kernel reads edge_out rows per node and averages in registers.
//   edge_out = relu([x[row]|x[col]|ea] @ We1 + be1) @ We2 + be2        [E,128]
//   mean     = segment_mean(edge_out, row)  via CSR gather              [N,128]
//   x_out    = relu([x|mean] @ Wn1 + bn1) @ Wn2 + bn2                   [N,128]
// d_out = [x_out | edge_out] in the detected float dtype.
//
// Workspace layout (bytes):
//   0         flags    2 ints
//   256       biasf    512 f32  [be1|be2|bn1|bn2]                2048
//   4096      WT1      [128][384] bf16 (We1^T)                  98304
//   102400    WT2      [128][128] bf16                          32768
//   135168    WnT1     [128][256] bf16                          65536
//   200704    WnT2     [128][128] bf16                          32768
//   233472    eidx32   [2][640000] int32                      5120000
//   5353472   ecnt     [50000] int  (histogram)                200000
//   5553472   cursor   [50000] int  (scatter cursors)          200000
//   5753472   rowstart [50001] int  (CSR offsets)              200004
//   5953536   perm     [640000] int (edges sorted by row)     2560000
//   8513536   meanb    [50000][128] bf16                     12800000
//   21313536  xb       [50000][128] bf16                     12800000
//   total ~34.1 MB
// ---------------------------------------------------------------------------

#define E_EDGES 640000
#define N_NODES 50000
#define DIM 128

typedef unsigned short u16;
typedef unsigned int u32x4 __attribute__((ext_vector_type(4)));
typedef float f32x4 __attribute__((ext_vector_type(4)));
typedef float f32x2 __attribute__((ext_vector_type(2)));
typedef short s16x8 __attribute__((ext_vector_type(8)));
union U16 { u32x4 u; s16x8 s; u16 h[8]; };

__device__ __forceinline__ float b2f(u16 u) {
  union { unsigned i; float f; } v; v.i = ((unsigned)u) << 16; return v.f;
}
__device__ __forceinline__ u16 f2b(float f) {
  union { float f; unsigned u; } v; v.f = f;
  unsigned r = v.u + 0x7FFFu + ((v.u >> 16) & 1u);
  return (u16)(r >> 16);
}
__device__ __forceinline__ float ldf(const void* p, long long i, int isF32) {
  return isF32 ? ((const float*)p)[i] : b2f(((const u16*)p)[i]);
}

// ----------------------------- dtype detector ------------------------------
__global__ void detect_kernel(const void* x, const void* ei, int* flags) {
  __shared__ int sBig, sNz;
  if (threadIdx.x == 0) { sBig = 0; sNz = 0; }
  __syncthreads();
  const u16* xu = (const u16*)x;
  const int* ew = (const int*)ei;
  int big = 0, nz = 0;
  for (int i = threadIdx.x; i < 4096; i += 256) {
    u16 u = xu[2 * i];                       // even half-words
    if (((u >> 7) & 0xFF) >= 0x90) big = 1;  // impossible for bf16 N(0,1)
    if (ew[2 * i + 1] != 0) nz = 1;          // odd words all 0 <=> int64
  }
  if (big) atomicOr(&sBig, 1);
  if (nz) atomicOr(&sNz, 1);
  __syncthreads();
  if (threadIdx.x == 0) { flags[0] = sBig; flags[1] = sNz ? 0 : 1; }
}

// --------------------------- index normalization ---------------------------
__global__ void normalize_idx(const void* ei, const int* __restrict__ flags,
                              int* __restrict__ out) {
  int i = blockIdx.x * 256 + threadIdx.x;   // grid covers 2*E exactly
  if (flags[1]) out[i] = (int)((const long long*)ei)[i];
  else          out[i] = ((const int*)ei)[i];
}

// --------------------------- weight prep (bf16^T) --------------------------
__global__ void prep_weights(const void* We1, const void* be1, const void* We2,
                             const void* be2, const void* Wn1, const void* bn1,
                             const void* Wn2, const void* bn2,
                             const int* __restrict__ flags,
                             u16* __restrict__ WT1, u16* __restrict__ WT2,
                             u16* __restrict__ WnT1, u16* __restrict__ WnT2,
                             float* __restrict__ biasf) {
  const int isF32 = flags[0];
  int tid = blockIdx.x * 256 + threadIdx.x;
  if (tid < 384 * 128) { int k = tid >> 7, n = tid & 127; WT1 [n * 384 + k] = f2b(ldf(We1, tid, isF32)); }
  if (tid < 128 * 128) { int k = tid >> 7, n = tid & 127; WT2 [n * 128 + k] = f2b(ldf(We2, tid, isF32)); }
  if (tid < 256 * 128) { int k = tid >> 7, n = tid & 127; WnT1[n * 256 + k] = f2b(ldf(Wn1, tid, isF32)); }
  if (tid < 128 * 128) { int k = tid >> 7, n = tid & 127; WnT2[n * 128 + k] = f2b(ldf(Wn2, tid, isF32)); }
  if (tid < 128) {
    biasf[tid]       = ldf(be1, tid, isF32);
    biasf[128 + tid] = ldf(be2, tid, isF32);
    biasf[256 + tid] = ldf(bn1, tid, isF32);
    biasf[384 + tid] = ldf(bn2, tid, isF32);
  }
}

// ------------------------------ x -> bf16 ----------------------------------
__global__ void convert_x(const void* x, const int* __restrict__ flags,
                          u16* __restrict__ xb) {
  int i = blockIdx.x * 256 + threadIdx.x;   // grid covers N*DIM exactly
  xb[i] = flags[0] ? f2b(((const float*)x)[i]) : ((const u16*)x)[i];
}

// -------------------------- counting-sort: histogram -----------------------
__global__ void hist_kernel(const int* __restrict__ ei,
                            int* __restrict__ ecnt) {
  const int e = blockIdx.x * 256 + threadIdx.x;   // grid covers E exactly
  atomicAdd(&ecnt[ei[e]], 1);
}

// -------------------------- counting-sort: scan ----------------------------
// Single block: 256 threads x 196-element serial chunks (256*196 = 50176).
#define SCAN_CHUNK 196
__global__ __launch_bounds__(256) void scan_kernel(
    const int* __restrict__ ecnt, int* __restrict__ rowstart) {
  __shared__ int sums[256];
  __shared__ int pref[257];
  const int t = threadIdx.x;
  const int base = t * SCAN_CHUNK;
  int s = 0;
  for (int i = 0; i < SCAN_CHUNK; ++i) {
    const int idx = base + i;
    if (idx < N_NODES) s += ecnt[idx];
  }
  sums[t] = s;
  __syncthreads();
  if (t == 0) {
    int run = 0;
    for (int i = 0; i < 256; ++i) { pref[i] = run; run += sums[i]; }
    pref[256] = run;
  }
  __syncthreads();
  int run = pref[t];
  for (int i = 0; i < SCAN_CHUNK; ++i) {
    const int idx = base + i;
    if (idx < N_NODES) { rowstart[idx] = run; run += ecnt[idx]; }
  }
  if (t == 0) rowstart[N_NODES] = pref[256];
}

// -------------------------- counting-sort: scatter -------------------------
__global__ void scatter_kernel(const int* __restrict__ ei,
                               const int* __restrict__ rowstart,
                               int* __restrict__ cursor,
                               int* __restrict__ perm) {
  const int e = blockIdx.x * 256 + threadIdx.x;   // grid covers E exactly
  const int r = ei[e];
  const int pos = rowstart[r] + atomicAdd(&cursor[r], 1);
  perm[pos] = e;
}

// ------------------------------ edge kernel --------------------------------
// block = 256 thr (4 waves), wave = 32 edges (2 M-tiles of 16), grid = E/128.
// MFMA 16x16x32 bf16: A[m=lane&15][k=quad*8+j], B[n=lane&15][k=quad*8+j],
//                     D[row=quad*4+r][col=lane&15].
// No atomics: only computes edge_out and streams it to d_out (coalesced).
__global__ __launch_bounds__(256) void edge_kernel(
    const u16* __restrict__ xb, const int* __restrict__ ei, const void* ea,
    const u16* __restrict__ WT1, const u16* __restrict__ WT2,
    const float* __restrict__ biasf, const int* __restrict__ flags,
    void* d_out) {
  __shared__ u16 h[4][32 * 136];   // per-wave 32x128 hidden tile, stride 136
  const int isF32 = flags[0];
  const int wid = threadIdx.x >> 6, lane = threadIdx.x & 63;
  const int lm = lane & 15, quad = lane >> 4;
  const int ebase = (blockIdx.x * 4 + wid) * 32;

  const int e0 = ebase + lm, e1 = ebase + 16 + lm;
  const int row0 = ei[e0], col0 = ei[E_EDGES + e0];
  const int row1 = ei[e1], col1 = ei[E_EDGES + e1];

  const f32x4 fz = {0.f, 0.f, 0.f, 0.f};
  f32x4 acc[2][8];
#pragma unroll
  for (int mt = 0; mt < 2; ++mt)
#pragma unroll
    for (int t = 0; t < 8; ++t) acc[mt][t] = fz;

  // ---- layer 1: [32,384] @ [384,128] ----
#pragma unroll
  for (int ks = 0; ks < 12; ++ks) {
    const int k0 = ks * 32 + quad * 8;
    U16 a0, a1;
    if (k0 < 256) {
      const u16 *p0, *p1;
      if (k0 < 128) { p0 = xb + (size_t)row0 * DIM + k0;         p1 = xb + (size_t)row1 * DIM + k0; }
      else          { p0 = xb + (size_t)col0 * DIM + (k0 - 128); p1 = xb + (size_t)col1 * DIM + (k0 - 128); }
      a0.u = *(const u32x4*)p0;
      a1.u = *(const u32x4*)p1;
    } else {
      const int off = k0 - 256;
      if (isF32) {
        const float* q0 = (const float*)ea + (size_t)e0 * DIM + off;
        const float* q1 = (const float*)ea + (size_t)e1 * DIM + off;
        f32x4 lo0 = *(const f32x4*)q0, hi0 = *(const f32x4*)(q0 + 4);
        f32x4 lo1 = *(const f32x4*)q1, hi1 = *(const f32x4*)(q1 + 4);
#pragma unroll
        for (int j = 0; j < 4; ++j) {
          a0.h[j] = f2b(lo0[j]); a0.h[4 + j] = f2b(hi0[j]);
          a1.h[j] = f2b(lo1[j]); a1.h[4 + j] = f2b(hi1[j]);
        }
      } else {
        const u16* q0 = (const u16*)ea + (size_t)e0 * DIM + off;
        const u16* q1 = (const u16*)ea + (size_t)e1 * DIM + off;
        a0.u = *(const u32x4*)q0;
        a1.u = *(const u32x4*)q1;
      }
    }
#pragma unroll
    for (int t = 0; t < 8; ++t) {
      U16 b; b.u = *(const u32x4*)(WT1 + (t * 16 + lm) * 384 + k0);
      acc[0][t] = __builtin_amdgcn_mfma_f32_16x16x32_bf16(a0.s, b.s, acc[0][t], 0, 0, 0);
      acc[1][t] = __builtin_amdgcn_mfma_f32_16x16x32_bf16(a1.s, b.s, acc[1][t], 0, 0, 0);
    }
  }

  // bias + relu -> LDS (bf16)
  u16* hw = h[wid];
#pragma unroll
  for (int t = 0; t < 8; ++t) {
    const int n = t * 16 + lm;
    const float bias = biasf[n];           // be1
#pragma unroll
    for (int mt = 0; mt < 2; ++mt)
#pragma unroll
      for (int r = 0; r < 4; ++r) {
        float v = acc[mt][t][r] + bias;
        v = v > 0.f ? v : 0.f;
        hw[(mt * 16 + quad * 4 + r) * 136 + n] = f2b(v);
      }
  }
  __syncthreads();

  // ---- layer 2: [32,128] @ [128,128] ----
  f32x4 acc2[2][8];
#pragma unroll
  for (int mt = 0; mt < 2; ++mt)
#pragma unroll
    for (int t = 0; t < 8; ++t) acc2[mt][t] = fz;

#pragma unroll
  for (int ks = 0; ks < 4; ++ks) {
    const int k0 = ks * 32 + quad * 8;
    U16 a0, a1;
    a0.u = *(const u32x4*)(hw + lm * 136 + k0);
    a1.u = *(const u32x4*)(hw + (16 + lm) * 136 + k0);
#pragma unroll
    for (int t = 0; t < 8; ++t) {
      U16 b; b.u = *(const u32x4*)(WT2 + (t * 16 + lm) * 128 + k0);
      acc2[0][t] = __builtin_amdgcn_mfma_f32_16x16x32_bf16(a0.s, b.s, acc2[0][t], 0, 0, 0);
      acc2[1][t] = __builtin_amdgcn_mfma_f32_16x16x32_bf16(a1.s, b.s, acc2[1][t], 0, 0, 0);
    }
  }

  // epilogue: bias + store edge_out in detected dtype (coalesced 64B/quad)
  float* eoutf = (float*)d_out + (size_t)N_NODES * DIM;
  u16*   eoutb = (u16*)d_out   + (size_t)N_NODES * DIM;

#pragma unroll
  for (int t = 0; t < 8; ++t) {
    const int n = t * 16 + lm;
    const float bias = biasf[128 + n];     // be2
#pragma unroll
    for (int mt = 0; mt < 2; ++mt)
#pragma unroll
      for (int r = 0; r < 4; ++r) {
        float v = acc2[mt][t][r] + bias;
        const size_t e = (size_t)(ebase + mt * 16 + quad * 4 + r);
        if (isF32) eoutf[e * DIM + n] = v;
        else       eoutb[e * DIM + n] = f2b(v);
      }
  }
}

// ---------------------------- segment-mean kernel --------------------------
// One wave per node; lane owns features {2*lane, 2*lane+1}. Each edge row of
// edge_out is read as one contiguous 512B (f32) / 256B (bf16) wave segment.
// No atomics; count = rowstart[n+1]-rowstart[n].
__global__ __launch_bounds__(256) void agg_kernel(
    const void* d_out, const int* __restrict__ rowstart,
    const int* __restrict__ perm, const int* __restrict__ flags,
    u16* __restrict__ meanb) {
  const int isF32 = flags[0];
  const int wid = threadIdx.x >> 6, lane = threadIdx.x & 63;
  const int node = blockIdx.x * 4 + wid;
  if (node >= N_NODES) return;
  const int beg = rowstart[node], end = rowstart[node + 1];
  float s0 = 0.f, s1 = 0.f;
  if (isF32) {
    const float* base = (const float*)d_out + (size_t)N_NODES * DIM;
    int j = beg;
    for (; j + 2 <= end; j += 2) {
      const int ea0 = perm[j], ea1 = perm[j + 1];
      const f32x2 v0 = *(const f32x2*)(base + (size_t)ea0 * DIM + lane * 2);
      const f32x2 v1 = *(const f32x2*)(base + (size_t)ea1 * DIM + lane * 2);
      s0 += v0.x + v1.x; s1 += v0.y + v1.y;
    }
    if (j < end) {
      const int ea0 = perm[j];
      const f32x2 v0 = *(const f32x2*)(base + (size_t)ea0 * DIM + lane * 2);
      s0 += v0.x; s1 += v0.y;
    }
  } else {
    const u16* base = (const u16*)d_out + (size_t)N_NODES * DIM;
    int j = beg;
    for (; j + 2 <= end; j += 2) {
      const int ea0 = perm[j], ea1 = perm[j + 1];
      const unsigned v0 = *(const unsigned*)(base + (size_t)ea0 * DIM + lane * 2);
      const unsigned v1 = *(const unsigned*)(base + (size_t)ea1 * DIM + lane * 2);
      s0 += b2f((u16)(v0 & 0xFFFF)) + b2f((u16)(v1 & 0xFFFF));
      s1 += b2f((u16)(v0 >> 16)) + b2f((u16)(v1 >> 16));
    }
    if (j < end) {
      const int ea0 = perm[j];
      const unsigned v0 = *(const unsigned*)(base + (size_t)ea0 * DIM + lane * 2);
      s0 += b2f((u16)(v0 & 0xFFFF));
      s1 += b2f((u16)(v0 >> 16));
    }
  }
  const float inv = 1.0f / fmaxf((float)(end - beg), 1.0f);
  const unsigned out = ((unsigned)f2b(s1 * inv) << 16) | (unsigned)f2b(s0 * inv);
  *(unsigned*)(meanb + (size_t)node * DIM + lane * 2) = out;
}

// ------------------------------ node kernel --------------------------------
__global__ __launch_bounds__(256) void node_kernel(
    const u16* __restrict__ xb, const u16* __restrict__ meanb,
    const u16* __restrict__ WnT1, const u16* __restrict__ WnT2,
    const float* __restrict__ biasf, const int* __restrict__ flags,
    void* d_out) {
  __shared__ u16 h[4][32 * 136];
  const int isF32 = flags[0];
  const int wid = threadIdx.x >> 6, lane = threadIdx.x & 63;
  const int lm = lane & 15, quad = lane >> 4;
  const int nbase = (blockIdx.x * 4 + wid) * 32;

  int nd0 = nbase + lm;      if (nd0 > N_NODES - 1) nd0 = N_NODES - 1;
  int nd1 = nbase + 16 + lm; if (nd1 > N_NODES - 1) nd1 = N_NODES - 1;

  const f32x4 fz = {0.f, 0.f, 0.f, 0.f};
  f32x4 acc[2][8];
#pragma unroll
  for (int mt = 0; mt < 2; ++mt)
#pragma unroll
    for (int t = 0; t < 8; ++t) acc[mt][t] = fz;

  // ---- layer 1: [32,256] @ [256,128] ----
#pragma unroll
  for (int ks = 0; ks < 8; ++ks) {
    const int k0 = ks * 32 + quad * 8;
    const u16 *p0, *p1;
    if (k0 < 128) { p0 = xb + (size_t)nd0 * DIM + k0;            p1 = xb + (size_t)nd1 * DIM + k0; }
    else          { p0 = meanb + (size_t)nd0 * DIM + (k0 - 128); p1 = meanb + (size_t)nd1 * DIM + (k0 - 128); }
    U16 a0, a1;
    a0.u = *(const u32x4*)p0;
    a1.u = *(const u32x4*)p1;
#pragma unroll
    for (int t = 0; t < 8; ++t) {
      U16 b; b.u = *(const u32x4*)(WnT1 + (t * 16 + lm) * 256 + k0);
      acc[0][t] = __builtin_amdgcn_mfma_f32_16x16x32_bf16(a0.s, b.s, acc[0][t], 0, 0, 0);
      acc[1][t] = __builtin_amdgcn_mfma_f32_16x16x32_bf16(a1.s, b.s, acc[1][t], 0, 0, 0);
    }
  }

  u16* hw = h[wid];
#pragma unroll
  for (int t = 0; t < 8; ++t) {
    const int n = t * 16 + lm;
    const float bias = biasf[256 + n];     // bn1
#pragma unroll
    for (int mt = 0; mt < 2; ++mt)
#pragma unroll
      for (int r = 0; r < 4; ++r) {
        float v = acc[mt][t][r] + bias;
        v = v > 0.f ? v : 0.f;
        hw[(mt * 16 + quad * 4 + r) * 136 + n] = f2b(v);
      }
  }
  __syncthreads();

  // ---- layer 2: [32,128] @ [128,128] ----
  f32x4 acc2[2][8];
#pragma unroll
  for (int mt = 0; mt < 2; ++mt)
#pragma unroll
    for (int t = 0; t < 8; ++t) acc2[mt][t] = fz;

#pragma unroll
  for (int ks = 0; ks < 4; ++ks) {
    const int k0 = ks * 32 + quad * 8;
    U16 a0, a1;
    a0.u = *(const u32x4*)(hw + lm * 136 + k0);
    a1.u = *(const u32x4*)(hw + (16 + lm) * 136 + k0);
#pragma unroll
    for (int t = 0; t < 8; ++t) {
      U16 b; b.u = *(const u32x4*)(WnT2 + (t * 16 + lm) * 128 + k0);
      acc2[0][t] = __builtin_amdgcn_mfma_f32_16x16x32_bf16(a0.s, b.s, acc2[0][t], 0, 0, 0);
      acc2[1][t] = __builtin_amdgcn_mfma_f32_16x16x32_bf16(a1.s, b.s, acc2[1][t], 0, 0, 0);
    }
  }

  float* xoutf = (float*)d_out;
  u16*   xoutb = (u16*)d_out;
#pragma unroll
  for (int t = 0; t < 8; ++t) {
    const int n = t * 16 + lm;
    const float bias = biasf[384 + n];     // bn2
#pragma unroll
    for (int mt = 0; mt < 2; ++mt)
#pragma unroll
      for (int r = 0; r < 4; ++r) {
        const int node = nbase + mt * 16 + quad * 4 + r;
        if (node < N_NODES) {
          float v = acc2[mt][t][r] + bias;
          if (isF32) xoutf[(size_t)node * DIM + n] = v;
          else       xoutb[(size_t)node * DIM + n] = f2b(v);
        }
      }
  }
}

// ------------------------------- launcher ----------------------------------
extern "C" void kernel_launch(void* const* d_in, const int* in_sizes, int n_in,
                              void* d_out, int out_size, void* d_ws, size_t ws_size,
                              hipStream_t stream) {
  const void* x   = d_in[0];
  const void* ei  = d_in[1];
  const void* ea  = d_in[2];
  const void* We1 = d_in[3]; const void* be1 = d_in[4];
  const void* We2 = d_in[5]; const void* be2 = d_in[6];
  const void* Wn1 = d_in[7]; const void* bn1 = d_in[8];
  const void* Wn2 = d_in[9]; const void* bn2 = d_in[10];

  char* ws = (char*)d_ws;
  int*   flags    = (int*)(ws + 0);
  float* biasf    = (float*)(ws + 256);
  u16*   WT1      = (u16*)(ws + 4096);
  u16*   WT2      = (u16*)(ws + 102400);
  u16*   WnT1     = (u16*)(ws + 135168);
  u16*   WnT2     = (u16*)(ws + 200704);
  int*   eidx32   = (int*)(ws + 233472);
  int*   ecnt     = (int*)(ws + 5353472);
  int*   cursor   = (int*)(ws + 5553472);
  int*   rowstart = (int*)(ws + 5753472);
  int*   perm     = (int*)(ws + 5953536);
  u16*   meanb    = (u16*)(ws + 8513536);
  u16*   xb       = (u16*)(ws + 21313536);

  // zero histogram + scatter cursors (400 KB, contiguous)
  hipMemsetAsync(ws + 5353472, 0, 400000, stream);

  detect_kernel<<<1, 256, 0, stream>>>(x, ei, flags);
  normalize_idx<<<2 * E_EDGES / 256, 256, 0, stream>>>(ei, flags, eidx32);
  prep_weights<<<192, 256, 0, stream>>>(We1, be1, We2, be2, Wn1, bn1, Wn2, bn2,
                                        flags, WT1, WT2, WnT1, WnT2, biasf);
  convert_x<<<N_NODES * DIM / 256, 256, 0, stream>>>(x, flags, xb);

  // counting sort by row -> CSR (rowstart, perm)
  hist_kernel<<<E_EDGES / 256, 256, 0, stream>>>(eidx32, ecnt);
  scan_kernel<<<1, 256, 0, stream>>>(ecnt, rowstart);
  scatter_kernel<<<E_EDGES / 256, 256, 0, stream>>>(eidx32, rowstart, cursor, perm);

  edge_kernel<<<E_EDGES / 128, 256, 0, stream>>>(xb, eidx32, ea, WT1, WT2,
                                                 biasf, flags, d_out);
  agg_kernel<<<N_NODES / 4, 256, 0, stream>>>(d_out, rowstart, perm, flags, meanb);
  node_kernel<<<(N_NODES + 127) / 128, 256, 0, stream>>>(xb, meanb, WnT1, WnT2,
                                                         biasf, flags, d_out);
}

// Round 2
// 1170.651 us; speedup vs baseline: 1.0052x; 1.0052x over previous
//
#include <hip/hip_runtime.h>
#include <stdint.h>

// ---------------------------------------------------------------------------
// GNN MetaLayer on MI355X (gfx950). Dtype-self-detecting:
//   flags[0] = 1 if float tensors are f32 (else bf16), detected from x bits
//   flags[1] = 1 if edge_index is int64 (else int32), detected from odd words
// Compute: bf16 MFMA 16x16x32, f32 accumulate.
// Aggregation: NO float atomics. Counting-sort edges by row (fused
// normalize+histogram + single-block scan + scatter -> perm/rowstart CSR),
// then a gather-based segment-mean kernel averages edge_out rows per node.
//   edge_out = relu([x[row]|x[col]|ea] @ We1 + be1) @ We2 + be2        [E,128]
//   mean     = segment_mean(edge_out, row)  via CSR gather              [N,128]
//   x_out    = relu([x|mean] @ Wn1 + bn1) @ Wn2 + bn2                   [N,128]
// d_out = [x_out | edge_out] in the detected float dtype.
//
// Round-2 changes (latency-bound edge kernel, VGPR=80 had no room for ILP):
//   * edge_kernel: preload ALL 24 A-fragments (xb row/col gathers + ea) into
//     registers before the MFMA loop -> ~24 outstanding loads per wave.
//     __launch_bounds__(256,2) permits up to 256 VGPR.
//   * node_kernel: 16 nodes/wave (782 blocks instead of 391), A preloaded.
//   * agg_kernel: 4 independent edge-row gathers in flight.
//   * normalize_idx + hist fused.
//
// Workspace layout (bytes):
//   0         flags    2 ints
//   256       biasf    512 f32  [be1|be2|bn1|bn2]                2048
//   4096      WT1      [128][384] bf16 (We1^T)                  98304
//   102400    WT2      [128][128] bf16                          32768
//   135168    WnT1     [128][256] bf16                          65536
//   200704    WnT2     [128][128] bf16                          32768
//   233472    eidx32   [2][640000] int32                      5120000
//   5353472   ecnt     [50000] int  (histogram)                200000
//   5553472   cursor   [50000] int  (scatter cursors)          200000
//   5753472   rowstart [50001] int  (CSR offsets)              200004
//   5953536   perm     [640000] int (edges sorted by row)     2560000
//   8513536   meanb    [50000][128] bf16                     12800000
//   21313536  xb       [50000][128] bf16                     12800000
//   total ~34.1 MB
// ---------------------------------------------------------------------------

#define E_EDGES 640000
#define N_NODES 50000
#define DIM 128

typedef unsigned short u16;
typedef unsigned int u32x4 __attribute__((ext_vector_type(4)));
typedef float f32x4 __attribute__((ext_vector_type(4)));
typedef float f32x2 __attribute__((ext_vector_type(2)));
typedef short s16x8 __attribute__((ext_vector_type(8)));
union U16 { u32x4 u; s16x8 s; u16 h[8]; };

__device__ __forceinline__ float b2f(u16 u) {
  union { unsigned i; float f; } v; v.i = ((unsigned)u) << 16; return v.f;
}
__device__ __forceinline__ u16 f2b(float f) {
  union { float f; unsigned u; } v; v.f = f;
  unsigned r = v.u + 0x7FFFu + ((v.u >> 16) & 1u);
  return (u16)(r >> 16);
}
__device__ __forceinline__ float ldf(const void* p, long long i, int isF32) {
  return isF32 ? ((const float*)p)[i] : b2f(((const u16*)p)[i]);
}

// ----------------------------- dtype detector ------------------------------
__global__ void detect_kernel(const void* x, const void* ei, int* flags) {
  __shared__ int sBig, sNz;
  if (threadIdx.x == 0) { sBig = 0; sNz = 0; }
  __syncthreads();
  const u16* xu = (const u16*)x;
  const int* ew = (const int*)ei;
  int big = 0, nz = 0;
  for (int i = threadIdx.x; i < 4096; i += 256) {
    u16 u = xu[2 * i];                       // even half-words
    if (((u >> 7) & 0xFF) >= 0x90) big = 1;  // impossible for bf16 N(0,1)
    if (ew[2 * i + 1] != 0) nz = 1;          // odd words all 0 <=> int64
  }
  if (big) atomicOr(&sBig, 1);
  if (nz) atomicOr(&sNz, 1);
  __syncthreads();
  if (threadIdx.x == 0) { flags[0] = sBig; flags[1] = sNz ? 0 : 1; }
}

// ---------------- index normalization + row histogram (fused) --------------
__global__ void normalize_hist(const void* ei, const int* __restrict__ flags,
                               int* __restrict__ out, int* __restrict__ ecnt) {
  int i = blockIdx.x * 256 + threadIdx.x;   // grid covers 2*E exactly
  int v;
  if (flags[1]) v = (int)((const long long*)ei)[i];
  else          v = ((const int*)ei)[i];
  out[i] = v;
  if (i < E_EDGES) atomicAdd(&ecnt[v], 1);  // rows only
}

// --------------------------- weight prep (bf16^T) --------------------------
__global__ void prep_weights(const void* We1, const void* be1, const void* We2,
                             const void* be2, const void* Wn1, const void* bn1,
                             const void* Wn2, const void* bn2,
                             const int* __restrict__ flags,
                             u16* __restrict__ WT1, u16* __restrict__ WT2,
                             u16* __restrict__ WnT1, u16* __restrict__ WnT2,
                             float* __restrict__ biasf) {
  const int isF32 = flags[0];
  int tid = blockIdx.x * 256 + threadIdx.x;
  if (tid < 384 * 128) { int k = tid >> 7, n = tid & 127; WT1 [n * 384 + k] = f2b(ldf(We1, tid, isF32)); }
  if (tid < 128 * 128) { int k = tid >> 7, n = tid & 127; WT2 [n * 128 + k] = f2b(ldf(We2, tid, isF32)); }
  if (tid < 256 * 128) { int k = tid >> 7, n = tid & 127; WnT1[n * 256 + k] = f2b(ldf(Wn1, tid, isF32)); }
  if (tid < 128 * 128) { int k = tid >> 7, n = tid & 127; WnT2[n * 128 + k] = f2b(ldf(Wn2, tid, isF32)); }
  if (tid < 128) {
    biasf[tid]       = ldf(be1, tid, isF32);
    biasf[128 + tid] = ldf(be2, tid, isF32);
    biasf[256 + tid] = ldf(bn1, tid, isF32);
    biasf[384 + tid] = ldf(bn2, tid, isF32);
  }
}

// ------------------------------ x -> bf16 ----------------------------------
__global__ void convert_x(const void* x, const int* __restrict__ flags,
                          u16* __restrict__ xb) {
  int i = blockIdx.x * 256 + threadIdx.x;   // grid covers N*DIM exactly
  xb[i] = flags[0] ? f2b(((const float*)x)[i]) : ((const u16*)x)[i];
}

// -------------------------- counting-sort: scan ----------------------------
// Single block: 256 threads x 196-element serial chunks (256*196 = 50176).
#define SCAN_CHUNK 196
__global__ __launch_bounds__(256) void scan_kernel(
    const int* __restrict__ ecnt, int* __restrict__ rowstart) {
  __shared__ int sums[256];
  __shared__ int pref[257];
  const int t = threadIdx.x;
  const int base = t * SCAN_CHUNK;
  int s = 0;
  for (int i = 0; i < SCAN_CHUNK; ++i) {
    const int idx = base + i;
    if (idx < N_NODES) s += ecnt[idx];
  }
  sums[t] = s;
  __syncthreads();
  if (t == 0) {
    int run = 0;
    for (int i = 0; i < 256; ++i) { pref[i] = run; run += sums[i]; }
    pref[256] = run;
  }
  __syncthreads();
  int run = pref[t];
  for (int i = 0; i < SCAN_CHUNK; ++i) {
    const int idx = base + i;
    if (idx < N_NODES) { rowstart[idx] = run; run += ecnt[idx]; }
  }
  if (t == 0) rowstart[N_NODES] = pref[256];
}

// -------------------------- counting-sort: scatter -------------------------
__global__ void scatter_kernel(const int* __restrict__ ei,
                               const int* __restrict__ rowstart,
                               int* __restrict__ cursor,
                               int* __restrict__ perm) {
  const int e = blockIdx.x * 256 + threadIdx.x;   // grid covers E exactly
  const int r = ei[e];
  const int pos = rowstart[r] + atomicAdd(&cursor[r], 1);
  perm[pos] = e;
}

// ------------------------------ edge kernel --------------------------------
// block = 256 thr (4 waves), wave = 32 edges (2 M-tiles of 16), grid = E/128.
// MFMA 16x16x32 bf16: A[m=lane&15][k=quad*8+j], B[n=lane&15][k=quad*8+j],
//                     D[row=quad*4+r][col=lane&15].
// All 24 A-fragments (12 k-steps x 2 M-tiles) are preloaded before the MFMA
// loop so the random xb gathers + ea stream overlap (latency-bound fix).
__global__ __launch_bounds__(256, 2) void edge_kernel(
    const u16* __restrict__ xb, const int* __restrict__ ei, const void* ea,
    const u16* __restrict__ WT1, const u16* __restrict__ WT2,
    const float* __restrict__ biasf, const int* __restrict__ flags,
    void* d_out) {
  __shared__ u16 h[4][32 * 136];   // per-wave 32x128 hidden tile, stride 136
  const int isF32 = flags[0];
  const int wid = threadIdx.x >> 6, lane = threadIdx.x & 63;
  const int lm = lane & 15, quad = lane >> 4;
  const int ebase = (blockIdx.x * 4 + wid) * 32;

  const int e0 = ebase + lm, e1 = ebase + 16 + lm;
  const int row0 = ei[e0], col0 = ei[E_EDGES + e0];
  const int row1 = ei[e1], col1 = ei[E_EDGES + e1];

  // ---- preload all layer-1 A fragments (24 x 16B) ----
  U16 A0[12], A1[12];
  {
    const u16* r0 = xb + (size_t)row0 * DIM;
    const u16* r1 = xb + (size_t)row1 * DIM;
    const u16* c0 = xb + (size_t)col0 * DIM;
    const u16* c1 = xb + (size_t)col1 * DIM;
#pragma unroll
    for (int ks = 0; ks < 4; ++ks) {
      const int k0 = ks * 32 + quad * 8;
      A0[ks].u = *(const u32x4*)(r0 + k0);
      A1[ks].u = *(const u32x4*)(r1 + k0);
    }
#pragma unroll
    for (int ks = 4; ks < 8; ++ks) {
      const int k0 = (ks - 4) * 32 + quad * 8;
      A0[ks].u = *(const u32x4*)(c0 + k0);
      A1[ks].u = *(const u32x4*)(c1 + k0);
    }
    if (isF32) {
      const float* q0 = (const float*)ea + (size_t)e0 * DIM;
      const float* q1 = (const float*)ea + (size_t)e1 * DIM;
#pragma unroll
      for (int ks = 8; ks < 12; ++ks) {
        const int off = (ks - 8) * 32 + quad * 8;
        f32x4 lo0 = *(const f32x4*)(q0 + off), hi0 = *(const f32x4*)(q0 + off + 4);
        f32x4 lo1 = *(const f32x4*)(q1 + off), hi1 = *(const f32x4*)(q1 + off + 4);
#pragma unroll
        for (int j = 0; j < 4; ++j) {
          A0[ks].h[j] = f2b(lo0[j]); A0[ks].h[4 + j] = f2b(hi0[j]);
          A1[ks].h[j] = f2b(lo1[j]); A1[ks].h[4 + j] = f2b(hi1[j]);
        }
      }
    } else {
      const u16* q0 = (const u16*)ea + (size_t)e0 * DIM;
      const u16* q1 = (const u16*)ea + (size_t)e1 * DIM;
#pragma unroll
      for (int ks = 8; ks < 12; ++ks) {
        const int off = (ks - 8) * 32 + quad * 8;
        A0[ks].u = *(const u32x4*)(q0 + off);
        A1[ks].u = *(const u32x4*)(q1 + off);
      }
    }
  }

  const f32x4 fz = {0.f, 0.f, 0.f, 0.f};
  f32x4 acc[2][8];
#pragma unroll
  for (int mt = 0; mt < 2; ++mt)
#pragma unroll
    for (int t = 0; t < 8; ++t) acc[mt][t] = fz;

  // ---- layer 1: [32,384] @ [384,128] ----
#pragma unroll
  for (int ks = 0; ks < 12; ++ks) {
    const int k0 = ks * 32 + quad * 8;
#pragma unroll
    for (int t = 0; t < 8; ++t) {
      U16 b; b.u = *(const u32x4*)(WT1 + (t * 16 + lm) * 384 + k0);
      acc[0][t] = __builtin_amdgcn_mfma_f32_16x16x32_bf16(A0[ks].s, b.s, acc[0][t], 0, 0, 0);
      acc[1][t] = __builtin_amdgcn_mfma_f32_16x16x32_bf16(A1[ks].s, b.s, acc[1][t], 0, 0, 0);
    }
  }

  // bias + relu -> LDS (bf16)
  u16* hw = h[wid];
#pragma unroll
  for (int t = 0; t < 8; ++t) {
    const int n = t * 16 + lm;
    const float bias = biasf[n];           // be1
#pragma unroll
    for (int mt = 0; mt < 2; ++mt)
#pragma unroll
      for (int r = 0; r < 4; ++r) {
        float v = acc[mt][t][r] + bias;
        v = v > 0.f ? v : 0.f;
        hw[(mt * 16 + quad * 4 + r) * 136 + n] = f2b(v);
      }
  }
  __syncthreads();

  // ---- layer 2: [32,128] @ [128,128] ----
  f32x4 acc2[2][8];
#pragma unroll
  for (int mt = 0; mt < 2; ++mt)
#pragma unroll
    for (int t = 0; t < 8; ++t) acc2[mt][t] = fz;

#pragma unroll
  for (int ks = 0; ks < 4; ++ks) {
    const int k0 = ks * 32 + quad * 8;
    U16 a0, a1;
    a0.u = *(const u32x4*)(hw + lm * 136 + k0);
    a1.u = *(const u32x4*)(hw + (16 + lm) * 136 + k0);
#pragma unroll
    for (int t = 0; t < 8; ++t) {
      U16 b; b.u = *(const u32x4*)(WT2 + (t * 16 + lm) * 128 + k0);
      acc2[0][t] = __builtin_amdgcn_mfma_f32_16x16x32_bf16(a0.s, b.s, acc2[0][t], 0, 0, 0);
      acc2[1][t] = __builtin_amdgcn_mfma_f32_16x16x32_bf16(a1.s, b.s, acc2[1][t], 0, 0, 0);
    }
  }

  // epilogue: bias + store edge_out in detected dtype (coalesced 64B/quad)
  float* eoutf = (float*)d_out + (size_t)N_NODES * DIM;
  u16*   eoutb = (u16*)d_out   + (size_t)N_NODES * DIM;

#pragma unroll
  for (int t = 0; t < 8; ++t) {
    const int n = t * 16 + lm;
    const float bias = biasf[128 + n];     // be2
#pragma unroll
    for (int mt = 0; mt < 2; ++mt)
#pragma unroll
      for (int r = 0; r < 4; ++r) {
        float v = acc2[mt][t][r] + bias;
        const size_t e = (size_t)(ebase + mt * 16 + quad * 4 + r);
        if (isF32) eoutf[e * DIM + n] = v;
        else       eoutb[e * DIM + n] = f2b(v);
      }
  }
}

// ---------------------------- segment-mean kernel --------------------------
// One wave per node; lane owns features {2*lane, 2*lane+1}. Each edge row of
// edge_out is read as one contiguous 512B (f32) / 256B (bf16) wave segment.
// 4 independent gathers in flight per iteration. No atomics.
__global__ __launch_bounds__(256) void agg_kernel(
    const void* d_out, const int* __restrict__ rowstart,
    const int* __restrict__ perm, const int* __restrict__ flags,
    u16* __restrict__ meanb) {
  const int isF32 = flags[0];
  const int wid = threadIdx.x >> 6, lane = threadIdx.x & 63;
  const int node = blockIdx.x * 4 + wid;
  if (node >= N_NODES) return;
  const int beg = rowstart[node], end = rowstart[node + 1];
  float s0 = 0.f, s1 = 0.f;
  if (isF32) {
    const float* base = (const float*)d_out + (size_t)N_NODES * DIM;
    int j = beg;
    for (; j + 4 <= end; j += 4) {
      const int p0 = perm[j], p1 = perm[j + 1], p2 = perm[j + 2], p3 = perm[j + 3];
      const f32x2 v0 = *(const f32x2*)(base + (size_t)p0 * DIM + lane * 2);
      const f32x2 v1 = *(const f32x2*)(base + (size_t)p1 * DIM + lane * 2);
      const f32x2 v2 = *(const f32x2*)(base + (size_t)p2 * DIM + lane * 2);
      const f32x2 v3 = *(const f32x2*)(base + (size_t)p3 * DIM + lane * 2);
      s0 += v0.x + v1.x + v2.x + v3.x;
      s1 += v0.y + v1.y + v2.y + v3.y;
    }
    for (; j < end; ++j) {
      const f32x2 v0 = *(const f32x2*)(base + (size_t)perm[j] * DIM + lane * 2);
      s0 += v0.x; s1 += v0.y;
    }
  } else {
    const u16* base = (const u16*)d_out + (size_t)N_NODES * DIM;
    int j = beg;
    for (; j + 4 <= end; j += 4) {
      const int p0 = perm[j], p1 = perm[j + 1], p2 = perm[j + 2], p3 = perm[j + 3];
      const unsigned v0 = *(const unsigned*)(base + (size_t)p0 * DIM + lane * 2);
      const unsigned v1 = *(const unsigned*)(base + (size_t)p1 * DIM + lane * 2);
      const unsigned v2 = *(const unsigned*)(base + (size_t)p2 * DIM + lane * 2);
      const unsigned v3 = *(const unsigned*)(base + (size_t)p3 * DIM + lane * 2);
      s0 += b2f((u16)(v0 & 0xFFFF)) + b2f((u16)(v1 & 0xFFFF)) +
            b2f((u16)(v2 & 0xFFFF)) + b2f((u16)(v3 & 0xFFFF));
      s1 += b2f((u16)(v0 >> 16)) + b2f((u16)(v1 >> 16)) +
            b2f((u16)(v2 >> 16)) + b2f((u16)(v3 >> 16));
    }
    for (; j < end; ++j) {
      const unsigned v0 = *(const unsigned*)(base + (size_t)perm[j] * DIM + lane * 2);
      s0 += b2f((u16)(v0 & 0xFFFF));
      s1 += b2f((u16)(v0 >> 16));
    }
  }
  const float inv = 1.0f / fmaxf((float)(end - beg), 1.0f);
  const unsigned out = ((unsigned)f2b(s1 * inv) << 16) | (unsigned)f2b(s0 * inv);
  *(unsigned*)(meanb + (size_t)node * DIM + lane * 2) = out;
}

// ------------------------------ node kernel --------------------------------
// block = 256 thr (4 waves), wave = 16 nodes (1 M-tile), grid = ceil(N/64).
// A fragments preloaded (8 x 16B) for ILP; twice the blocks of the old
// 32-node-per-wave version for better CU balance.
__global__ __launch_bounds__(256) void node_kernel(
    const u16* __restrict__ xb, const u16* __restrict__ meanb,
    const u16* __restrict__ WnT1, const u16* __restrict__ WnT2,
    const float* __restrict__ biasf, const int* __restrict__ flags,
    void* d_out) {
  __shared__ u16 h[4][16 * 136];
  const int isF32 = flags[0];
  const int wid = threadIdx.x >> 6, lane = threadIdx.x & 63;
  const int lm = lane & 15, quad = lane >> 4;
  const int nbase = (blockIdx.x * 4 + wid) * 16;

  int nd0 = nbase + lm; if (nd0 > N_NODES - 1) nd0 = N_NODES - 1;

  // ---- preload layer-1 A fragments (8 x 16B) ----
  U16 A0[8];
  {
    const u16* r0 = xb    + (size_t)nd0 * DIM;
    const u16* m0 = meanb + (size_t)nd0 * DIM;
#pragma unroll
    for (int ks = 0; ks < 4; ++ks) {
      const int k0 = ks * 32 + quad * 8;
      A0[ks].u     = *(const u32x4*)(r0 + k0);
      A0[ks + 4].u = *(const u32x4*)(m0 + k0);
    }
  }

  const f32x4 fz = {0.f, 0.f, 0.f, 0.f};
  f32x4 acc[8];
#pragma unroll
  for (int t = 0; t < 8; ++t) acc[t] = fz;

  // ---- layer 1: [16,256] @ [256,128] ----
#pragma unroll
  for (int ks = 0; ks < 8; ++ks) {
    const int k0 = ks * 32 + quad * 8;
#pragma unroll
    for (int t = 0; t < 8; ++t) {
      U16 b; b.u = *(const u32x4*)(WnT1 + (t * 16 + lm) * 256 + k0);
      acc[t] = __builtin_amdgcn_mfma_f32_16x16x32_bf16(A0[ks].s, b.s, acc[t], 0, 0, 0);
    }
  }

  u16* hw = h[wid];
#pragma unroll
  for (int t = 0; t < 8; ++t) {
    const int n = t * 16 + lm;
    const float bias = biasf[256 + n];     // bn1
#pragma unroll
    for (int r = 0; r < 4; ++r) {
      float v = acc[t][r] + bias;
      v = v > 0.f ? v : 0.f;
      hw[(quad * 4 + r) * 136 + n] = f2b(v);
    }
  }
  __syncthreads();

  // ---- layer 2: [16,128] @ [128,128] ----
  f32x4 acc2[8];
#pragma unroll
  for (int t = 0; t < 8; ++t) acc2[t] = fz;

#pragma unroll
  for (int ks = 0; ks < 4; ++ks) {
    const int k0 = ks * 32 + quad * 8;
    U16 a0;
    a0.u = *(const u32x4*)(hw + lm * 136 + k0);
#pragma unroll
    for (int t = 0; t < 8; ++t) {
      U16 b; b.u = *(const u32x4*)(WnT2 + (t * 16 + lm) * 128 + k0);
      acc2[t] = __builtin_amdgcn_mfma_f32_16x16x32_bf16(a0.s, b.s, acc2[t], 0, 0, 0);
    }
  }

  float* xoutf = (float*)d_out;
  u16*   xoutb = (u16*)d_out;
#pragma unroll
  for (int t = 0; t < 8; ++t) {
    const int n = t * 16 + lm;
    const float bias = biasf[384 + n];     // bn2
#pragma unroll
    for (int r = 0; r < 4; ++r) {
      const int node = nbase + quad * 4 + r;
      if (node < N_NODES) {
        float v = acc2[t][r] + bias;
        if (isF32) xoutf[(size_t)node * DIM + n] = v;
        else       xoutb[(size_t)node * DIM + n] = f2b(v);
      }
    }
  }
}

// ------------------------------- launcher ----------------------------------
extern "C" void kernel_launch(void* const* d_in, const int* in_sizes, int n_in,
                              void* d_out, int out_size, void* d_ws, size_t ws_size,
                              hipStream_t stream) {
  const void* x   = d_in[0];
  const void* ei  = d_in[1];
  const void* ea  = d_in[2];
  const void* We1 = d_in[3]; const void* be1 = d_in[4];
  const void* We2 = d_in[5]; const void* be2 = d_in[6];
  const void* Wn1 = d_in[7]; const void* bn1 = d_in[8];
  const void* Wn2 = d_in[9]; const void* bn2 = d_in[10];

  char* ws = (char*)d_ws;
  int*   flags    = (int*)(ws + 0);
  float* biasf    = (float*)(ws + 256);
  u16*   WT1      = (u16*)(ws + 4096);
  u16*   WT2      = (u16*)(ws + 102400);
  u16*   WnT1     = (u16*)(ws + 135168);
  u16*   WnT2     = (u16*)(ws + 200704);
  int*   eidx32   = (int*)(ws + 233472);
  int*   ecnt     = (int*)(ws + 5353472);
  int*   cursor   = (int*)(ws + 5553472);
  int*   rowstart = (int*)(ws + 5753472);
  int*   perm     = (int*)(ws + 5953536);
  u16*   meanb    = (u16*)(ws + 8513536);
  u16*   xb       = (u16*)(ws + 21313536);

  // zero histogram + scatter cursors (400 KB, contiguous)
  hipMemsetAsync(ws + 5353472, 0, 400000, stream);

  detect_kernel<<<1, 256, 0, stream>>>(x, ei, flags);
  normalize_hist<<<2 * E_EDGES / 256, 256, 0, stream>>>(ei, flags, eidx32, ecnt);
  prep_weights<<<192, 256, 0, stream>>>(We1, be1, We2, be2, Wn1, bn1, Wn2, bn2,
                                        flags, WT1, WT2, WnT1, WnT2, biasf);
  convert_x<<<N_NODES * DIM / 256, 256, 0, stream>>>(x, flags, xb);

  // counting sort by row -> CSR (rowstart, perm)
  scan_kernel<<<1, 256, 0, stream>>>(ecnt, rowstart);
  scatter_kernel<<<E_EDGES / 256, 256, 0, stream>>>(eidx32, rowstart, cursor, perm);

  edge_kernel<<<E_EDGES / 128, 256, 0, stream>>>(xb, eidx32, ea, WT1, WT2,
                                                 biasf, flags, d_out);
  agg_kernel<<<N_NODES / 4, 256, 0, stream>>>(d_out, rowstart, perm, flags, meanb);
  node_kernel<<<(N_NODES + 63) / 64, 256, 0, stream>>>(xb, meanb, WnT1, WnT2,
                                                       biasf, flags, d_out);
}